// Round 3
// baseline (1879.104 us; speedup 1.0000x reference)
//
#include <hip/hip_runtime.h>
#include <stdint.h>

// JAX jax_threefry_partitionable=True semantics (verified exact, rounds 1-9).
// Round-13: PIPELINED SIM. R10/R11/R12 comparison (identical sim block, k_fused
// ~870/742/810) shows the single-CU sim chain (~25 us/step x 29) is the critical
// path, not the scan. New design: one sim block PER STEP (blocks 0..28). Block t
// computes its own uniforms while idle (uv array + scan rand-duty deleted),
// prefetches edge data after cnt[t]==EE, then polls stflag[t-1], reads packed
// prev-state (2.5 KB) + p-rows (out row t, written by block t-1 via relaxed
// AGENT stores = MALL write-through, the same proven producer/consumer protocol
// as edge_words), does edge+node phases, drains, publishes stflag[t]. Serial
// chain per step ~9 us => ~270 us total; per-step 240 KB output stores now
// overlap across 29 CUs. Scan: rolling 5-deep register pipeline, 20 rows/block,
// 1 LDS barrier per row, single end-of-block vmcnt(0) drain + one fetch_add.
constexpr int NN = 10000;          // nodes
constexpr int EE = 1000;           // hyperedges
constexpr int TT = 30;             // output rows
constexpr int TS = TT - 1;         // simulated steps
constexpr int ROW = NN * 3;        // floats per output row
constexpr int S_OFF = TT * ROW;    // state section offset in d_out
constexpr int CAP_E = 48;          // max nodes per edge (P(>=48) ~ 1e-30)
constexpr int WPR = CAP_E / 2;     // packed uint32 words per edge row
constexpr int PREW = 8;            // words prefetched unconditionally (covers ec<=16, ~97%)
constexpr int SIMT = 1024;         // block size (16 waves)
constexpr int NPT  = 10;           // nodes per thread, strided mapping n = tid + k*SIMT
constexpr int NROWS = TS * EE;     // 29000 total H rows
constexpr int F4R   = NN / 4;      // 2500 float4 per row
constexpr int RPB   = 20;          // H rows per scan block (divides EE => one t/block)
constexpr int PK    = 5;           // register pipeline depth in rows
constexpr int SCANB = NROWS / RPB; // 1450 scan blocks
constexpr int PACKW = (NN + 15) / 16;  // 625 words of 2-bit packed states
static_assert(EE % RPB == 0 && NROWS % RPB == 0 && RPB % PK == 0, "geometry");

// ---- Threefry-2x32, 20 rounds (exact JAX semantics), host+device ----
__host__ __device__ inline void tf2x32(uint32_t k0, uint32_t k1,
                                       uint32_t x0, uint32_t x1,
                                       uint32_t &o0, uint32_t &o1) {
  uint32_t ks2 = k0 ^ k1 ^ 0x1BD11BDAu;
  x0 += k0; x1 += k1;
#define TFR(r) do { x0 += x1; x1 = (x1 << (r)) | (x1 >> (32 - (r))); x1 ^= x0; } while (0)
  TFR(13); TFR(15); TFR(26); TFR(6);
  x0 += k1;  x1 += ks2 + 1u;
  TFR(17); TFR(29); TFR(16); TFR(24);
  x0 += ks2; x1 += k0 + 2u;
  TFR(13); TFR(15); TFR(26); TFR(6);
  x0 += k0;  x1 += k1 + 3u;
  TFR(17); TFR(29); TFR(16); TFR(24);
  x0 += k1;  x1 += ks2 + 4u;
  TFR(13); TFR(15); TFR(26); TFR(6);
  x0 += ks2; x1 += k0 + 5u;
#undef TFR
  o0 = x0; o1 = x1;
}

__device__ inline float bits_to_uniform(uint32_t bits) {
  float f = __uint_as_float((bits >> 9) | 0x3F800000u) - 1.0f;
  return f < 0.f ? 0.f : f;
}

struct StepKeys { uint32_t k1a[TS], k1b[TS], k2a[TS], k2b[TS]; };

// LDS-only barrier: orders LDS ops without draining global loads/stores (vmcnt).
__device__ inline void bar_lds() {
  asm volatile("s_waitcnt lgkmcnt(0)\n\ts_barrier" ::: "memory");
}

#define ALD(p)     __hip_atomic_load((p),  __ATOMIC_RELAXED, __HIP_MEMORY_SCOPE_AGENT)
#define AST(p, v)  __hip_atomic_store((p), (v), __ATOMIC_RELAXED, __HIP_MEMORY_SCOPE_AGENT)

// cnt/stflag live in d_ws (poisoned 0xAA every replay): zeroed before k_fused.
__global__ void k_zero(unsigned* __restrict__ cnt, unsigned* __restrict__ stflag) {
  if (threadIdx.x < TS) { cnt[threadIdx.x] = 0u; stflag[threadIdx.x] = 0u; }
}

__global__ __launch_bounds__(SIMT, 4)
void k_fused(const float* __restrict__ H,
             int* __restrict__ edge_cnt, uint32_t* __restrict__ edge_words,
             unsigned* __restrict__ stbuf, unsigned* __restrict__ stflag,
             unsigned* __restrict__ cntg,
             const float* __restrict__ x,
             const float* __restrict__ beta, const float* __restrict__ gamma_,
             float* __restrict__ out, StepKeys keys) {
  const int tid = threadIdx.x;
  const int bi  = blockIdx.x;

  if (bi >= TS) {
    // ---------- scan role: RPB consecutive rows, rolling PK-deep pipeline ----------
    const int base = (bi - TS) * RPB;
    const int t    = base / EE;          // single t per block (RPB | EE)
    const int e0   = base - t * EE;

    __shared__ int      scnt_arr[RPB];
    __shared__ uint16_t lists[RPB][CAP_E];
    if (tid < RPB) scnt_arr[tid] = 0;

    const float4* h0 = reinterpret_cast<const float4*>(H) + (size_t)base * F4R;
    const bool has2 = tid < F4R - 2048;  // tid < 452

    float4 b0[PK], b1[PK], b2[PK];
#pragma unroll
    for (int p = 0; p < PK; ++p) {       // prologue: PK rows (15 loads) in flight
      const float4* hr = h0 + (size_t)p * F4R;
      b0[p] = hr[tid];
      b1[p] = hr[tid + 1024];
      b2[p] = has2 ? hr[tid + 2048] : make_float4(0.f, 0.f, 0.f, 0.f);
    }
    bar_lds();                           // scnt_arr zeroed visible

#define PROCS(vv, b4, rr) do { \
    if ((vv).x != 0.f) { int q = atomicAdd(&scnt_arr[rr], 1); if (q < CAP_E) lists[rr][q] = (uint16_t)((b4) + 0); } \
    if ((vv).y != 0.f) { int q = atomicAdd(&scnt_arr[rr], 1); if (q < CAP_E) lists[rr][q] = (uint16_t)((b4) + 1); } \
    if ((vv).z != 0.f) { int q = atomicAdd(&scnt_arr[rr], 1); if (q < CAP_E) lists[rr][q] = (uint16_t)((b4) + 2); } \
    if ((vv).w != 0.f) { int q = atomicAdd(&scnt_arr[rr], 1); if (q < CAP_E) lists[rr][q] = (uint16_t)((b4) + 3); } \
  } while (0)

    for (int o = 0; o < RPB / PK; ++o) {
#pragma unroll
      for (int p = 0; p < PK; ++p) {     // static buffer index p: stays in VGPRs
        const int r = o * PK + p;
        float4 va = b0[p], vb = b1[p], vc = b2[p];
        if (o + 1 < RPB / PK) {          // refill row r+PK into slot p (uniform branch)
          const float4* hr = h0 + (size_t)(r + PK) * F4R;
          b0[p] = hr[tid];
          b1[p] = hr[tid + 1024];
          if (has2) b2[p] = hr[tid + 2048];
        }
        PROCS(va, 4 * tid, r);
        PROCS(vb, 4 * (tid + 1024), r);
        if (has2) PROCS(vc, 4 * (tid + 2048), r);
        bar_lds();                       // row r list complete (loads stay in flight)
        // publish row r (runs concurrently with next row's PROC, no extra barrier)
        int c = scnt_arr[r]; c = c < CAP_E ? c : CAP_E;
        const int row = base + r, e = e0 + r;
        if (tid == 0) AST(&edge_cnt[row], c);
        int words = (c + 1) >> 1;
        int wmax = words > PREW ? words : PREW;   // sentinel-pad for sim prefetch
        if (tid < wmax) {
          uint32_t lo = (2 * tid     < c) ? (uint32_t)lists[r][2 * tid]     : 0xFFFFu;
          uint32_t hi = (2 * tid + 1 < c) ? (uint32_t)lists[r][2 * tid + 1] : 0xFFFFu;
          AST(&edge_words[((size_t)t * WPR + tid) * EE + e], lo | (hi << 16));
        }
      }
    }
#undef PROCS
    __syncthreads();  // compiler emits s_waitcnt vmcnt(0): all edge stores at MALL
    if (tid == 0)
      __hip_atomic_fetch_add(&cntg[t], (unsigned)RPB,
                             __ATOMIC_RELAXED, __HIP_MEMORY_SCOPE_AGENT);
    return;
  }

  // ---------------- sim role: block t computes step t ----------------
  const int t = bi;
  __shared__ int      nvst[NN];        // 40 KB: bits 0-15 count, 16-17 state
  __shared__ unsigned stpack[PACKW];   // 2.5 KB packed 2-bit states

  // 1) off-chain prep: own uniforms (threefry), beta/gamma; t=0 also inits from x.
  float u1r[NPT], u2r[NPT], bet[NPT], gam[NPT], p0a[NPT], p1a[NPT], p2a[NPT];
#pragma unroll
  for (int k = 0; k < NPT; ++k) {
    int n = tid + k * SIMT;
    if (n < NN) {
      uint32_t a, b;
      tf2x32(keys.k1a[t], keys.k1b[t], 0u, (uint32_t)n, a, b);
      u1r[k] = bits_to_uniform(a ^ b);
      tf2x32(keys.k2a[t], keys.k2b[t], 0u, (uint32_t)n, a, b);
      u2r[k] = bits_to_uniform(a ^ b);
      bet[k] = beta[n]; gam[k] = gamma_[n];
    }
  }
  if (t == 0) {
    if (tid < PACKW) stpack[tid] = 0u;
#pragma unroll
    for (int k = 0; k < NPT; ++k) {
      int n = tid + k * SIMT;
      if (n < NN) {
        float x0 = x[n * 3 + 0], x1 = x[n * 3 + 1], x2 = x[n * 3 + 2];
        p0a[k] = x0; p1a[k] = x1; p2a[k] = x2;
        int st = (x1 == 1.f) ? 1 : ((x0 == 1.f) ? 0 : 2);
        nvst[n] = st << 16;
        out[n * 3 + 0] = x0; out[n * 3 + 1] = x1; out[n * 3 + 2] = x2;
        out[S_OFF + n * 3 + 0] = x0; out[S_OFF + n * 3 + 1] = x1; out[S_OFF + n * 3 + 2] = x2;
      }
    }
  }

  // 2) edge-data gate (scan producers); then prefetch edge words into regs.
  if (tid == 0) {
    while (ALD(&cntg[t]) < (unsigned)EE) __builtin_amdgcn_s_sleep(8);
  }
  bar_lds();
  int ec = 0; uint32_t w[PREW];
  const uint32_t* wb = edge_words + (size_t)t * WPR * EE + tid;
  if (tid < EE) {
    ec = ALD(&edge_cnt[t * EE + tid]); if (ec > CAP_E) ec = CAP_E;
#pragma unroll
    for (int j = 0; j < PREW; ++j) w[j] = ALD(&wb[(size_t)j * EE]);  // independent
  }

  // 3) serial-chain gate: prev block's state + p-rows; build nvst from packed state.
  if (t > 0) {
    if (tid == 0) {
      while (ALD(&stflag[t - 1]) == 0u) __builtin_amdgcn_s_sleep(8);
    }
    bar_lds();  // flag seen by all
    const float* pp = out + (size_t)t * ROW;   // p after step t-1 (AST-published)
#pragma unroll
    for (int k = 0; k < NPT; ++k) {            // issue early; consumed in node phase
      int n = tid + k * SIMT;
      if (n < NN) {
        p0a[k] = ALD(&pp[n * 3 + 0]);
        p1a[k] = ALD(&pp[n * 3 + 1]);
        p2a[k] = ALD(&pp[n * 3 + 2]);
      }
    }
    if (tid < PACKW) stpack[tid] = ALD(&stbuf[(size_t)(t - 1) * PACKW + tid]);
    bar_lds();  // stpack loaded
#pragma unroll
    for (int k = 0; k < NPT; ++k) {
      int n = tid + k * SIMT;
      if (n < NN) {
        int st = (int)((stpack[n >> 4] >> ((n & 15) * 2)) & 3u);
        nvst[n] = st << 16;
      }
    }
    bar_lds();  // nvst built; stpack reads done
    if (tid < PACKW) stpack[tid] = 0u;   // reuse for new state (overlaps edge phase)
  }

  // 4) edge phase: s = #infected members; scatter s into members' nvst low bits
  if (tid < EE) {
    int words = (ec + 1) >> 1;
    int s = 0;
#pragma unroll
    for (int j = 0; j < PREW; ++j) {
      uint32_t lo = w[j] & 0xFFFFu, hi = w[j] >> 16;
      if (lo != 0xFFFFu) s += ((nvst[lo] >> 16) == 1) ? 1 : 0;
      if (hi != 0xFFFFu) s += ((nvst[hi] >> 16) == 1) ? 1 : 0;
    }
    for (int j = PREW; j < words; ++j) {   // rare tail (ec > 16)
      uint32_t ww = ALD(&wb[(size_t)j * EE]);
      uint32_t lo = ww & 0xFFFFu, hi = ww >> 16;
      if (lo != 0xFFFFu) s += ((nvst[lo] >> 16) == 1) ? 1 : 0;
      if (hi != 0xFFFFu) s += ((nvst[hi] >> 16) == 1) ? 1 : 0;
    }
    if (s > 0) {  // adds can't carry into bit 16 (max sum 48000 < 65536)
#pragma unroll
      for (int j = 0; j < PREW; ++j) {
        uint32_t lo = w[j] & 0xFFFFu, hi = w[j] >> 16;
        if (lo != 0xFFFFu) atomicAdd(&nvst[lo], s);
        if (hi != 0xFFFFu) atomicAdd(&nvst[hi], s);
      }
      for (int j = PREW; j < words; ++j) {
        uint32_t ww = ALD(&wb[(size_t)j * EE]);
        uint32_t lo = ww & 0xFFFFu, hi = ww >> 16;
        if (lo != 0xFFFFu) atomicAdd(&nvst[lo], s);
        if (hi != 0xFFFFu) atomicAdd(&nvst[hi], s);
      }
    }
  }
  bar_lds();  // nvst counts complete; stpack zeroed

  // 5) node phase: advance p, draw transitions, write rows, pack new state.
  float* po = out + (size_t)(t + 1) * ROW;          // read by block t+1 => AST
  float* so = out + S_OFF + (size_t)(t + 1) * ROW;  // host-only => plain
#pragma unroll
  for (int k = 0; k < NPT; ++k) {
    int n = tid + k * SIMT;
    if (n < NN) {
      int wv = nvst[n];
      int v  = wv & 0xFFFF;
      int st = wv >> 16;
      float s1 = (st == 1) ? 1.f : 0.f;
      float new_cases = __fmul_rn(bet[k], (float)v);
      float new_rec   = __fmul_rn(gam[k], s1);
      float q0 = fminf(1.f, fmaxf(0.f, __fsub_rn(p0a[k], new_cases)));
      float q1 = fminf(1.f, fmaxf(0.f, __fsub_rn(__fadd_rn(p1a[k], new_cases), new_rec)));
      float q2 = fminf(1.f, fmaxf(0.f, __fadd_rn(p2a[k], new_rec)));

      bool was_S  = (st == 0);
      bool was_I  = (st == 1);
      bool s_to_I = was_S && (u1r[k] < q1);
      bool i_event = was_I && (u1r[k] < q2);
      bool u2lt   = (u2r[k] < 0.5f);
      bool i_to_R = i_event && u2lt;
      bool i_to_S = i_event && !u2lt;
      bool new_S = (was_S && !s_to_I) || i_to_S;
      bool new_I = s_to_I || (was_I && !i_event);
      bool new_R = (!was_S && !was_I) || i_to_R;

      AST(&po[n * 3 + 0], q0);
      AST(&po[n * 3 + 1], q1);
      AST(&po[n * 3 + 2], q2);
      so[n * 3 + 0] = new_S ? 1.f : 0.f;
      so[n * 3 + 1] = new_I ? 1.f : 0.f;
      so[n * 3 + 2] = new_R ? 1.f : 0.f;
      int stn = new_I ? 1 : (new_S ? 0 : 2);
      atomicOr(&stpack[n >> 4], (unsigned)stn << ((n & 15) * 2));
    }
  }
  bar_lds();  // stpack complete
  if (tid < PACKW) AST(&stbuf[(size_t)t * PACKW + tid], stpack[tid]);
  __syncthreads();  // s_waitcnt vmcnt(0): p rows + stbuf at MALL
  if (tid == 0) AST(&stflag[t], 1u);
}

extern "C" void kernel_launch(void* const* d_in, const int* in_sizes, int n_in,
                              void* d_out, int out_size, void* d_ws, size_t ws_size,
                              hipStream_t stream) {
  const float* x      = (const float*)d_in[0];
  const float* H      = (const float*)d_in[1];
  const float* beta   = (const float*)d_in[2];
  const float* gamma_ = (const float*)d_in[3];
  float* out = (float*)d_out;

  // key chain: key0 = jax.random.key(42) = (0,42); split(key,3) partitionable:
  // subkey i = threefry(key, (0,i)); carry = subkey 0.
  StepKeys keys;
  uint32_t key0 = 0u, key1 = 42u;
  for (int t = 0; t < TS; ++t) {
    uint32_t a0, b0, a1, b1, a2, b2;
    tf2x32(key0, key1, 0u, 0u, a0, b0);
    tf2x32(key0, key1, 0u, 1u, a1, b1);
    tf2x32(key0, key1, 0u, 2u, a2, b2);
    keys.k1a[t] = a1; keys.k1b[t] = b1; keys.k2a[t] = a2; keys.k2b[t] = b2;
    key0 = a0; key1 = b0;
  }

  // workspace layout (~3 MB)
  size_t off = 0;
  auto take = [&](size_t bytes) { size_t o = off; off += (bytes + 255) & ~(size_t)255; return o; };
  size_t o_ec = take((size_t)TS * EE * sizeof(int));
  size_t o_ew = take((size_t)TS * WPR * EE * sizeof(uint32_t));
  size_t o_sb = take((size_t)TS * PACKW * sizeof(unsigned));
  size_t o_ct = take((size_t)TS * sizeof(unsigned));
  size_t o_fl = take((size_t)TS * sizeof(unsigned));

  int*      edge_cnt   = (int*)((char*)d_ws + o_ec);
  uint32_t* edge_words = (uint32_t*)((char*)d_ws + o_ew);
  unsigned* stbuf      = (unsigned*)((char*)d_ws + o_sb);
  unsigned* cnt        = (unsigned*)((char*)d_ws + o_ct);
  unsigned* stflag     = (unsigned*)((char*)d_ws + o_fl);

  k_zero<<<1, 64, 0, stream>>>(cnt, stflag);
  k_fused<<<TS + SCANB, SIMT, 0, stream>>>(H, edge_cnt, edge_words, stbuf, stflag,
                                           cnt, x, beta, gamma_, out, keys);
}

// Round 5
// 1864.987 us; speedup vs baseline: 1.0076x; 1.0076x over previous
//
#include <hip/hip_runtime.h>
#include <stdint.h>

// JAX jax_threefry_partitionable=True semantics (verified exact, rounds 1-9).
// Round-15: R14 with the state-handoff bug fixed. R14 failed (absmax 0.98)
// because STW=2500 > SIMT=1024: `if (tid < STW)` restore/publish moved only the
// first 1024 dwords of the 10KB byte-state buffer -- nodes 4096..9999 got
// garbage state each step. Fix: strided loops (i = tid; i < STW; i += SIMT).
// Design otherwise identical to R14: pipelined sim (one block per step),
// two-flag handoff (state bytes first w/ tiny drain, then p-rows; host-only
// s-rows fully off-chain), st8 byte states (no atomicOr pack, no nvst rebuild),
// counts-only nvst zeroed off-chain, s_sleep(1) chain polls.
constexpr int NN = 10000;          // nodes
constexpr int EE = 1000;           // hyperedges
constexpr int TT = 30;             // output rows
constexpr int TS = TT - 1;         // simulated steps
constexpr int ROW = NN * 3;        // floats per output row
constexpr int S_OFF = TT * ROW;    // state section offset in d_out
constexpr int CAP_E = 48;          // max nodes per edge (P(>=48) ~ 1e-30)
constexpr int WPR = CAP_E / 2;     // packed uint32 words per edge row
constexpr int PREW = 8;            // words prefetched unconditionally (covers ec<=16, ~97%)
constexpr int SIMT = 1024;         // block size (16 waves)
constexpr int NPT  = 10;           // nodes per thread, strided mapping n = tid + k*SIMT
constexpr int NROWS = TS * EE;     // 29000 total H rows
constexpr int F4R   = NN / 4;      // 2500 float4 per row
constexpr int RPB   = 20;          // H rows per scan block (divides EE => one t/block)
constexpr int PK    = 5;           // register pipeline depth in rows
constexpr int SCANB = NROWS / RPB; // 1450 scan blocks
constexpr int STW   = NN / 4;      // 2500 dwords of byte-packed states
static_assert(EE % RPB == 0 && NROWS % RPB == 0 && RPB % PK == 0, "geometry");

// ---- Threefry-2x32, 20 rounds (exact JAX semantics), host+device ----
__host__ __device__ inline void tf2x32(uint32_t k0, uint32_t k1,
                                       uint32_t x0, uint32_t x1,
                                       uint32_t &o0, uint32_t &o1) {
  uint32_t ks2 = k0 ^ k1 ^ 0x1BD11BDAu;
  x0 += k0; x1 += k1;
#define TFR(r) do { x0 += x1; x1 = (x1 << (r)) | (x1 >> (32 - (r))); x1 ^= x0; } while (0)
  TFR(13); TFR(15); TFR(26); TFR(6);
  x0 += k1;  x1 += ks2 + 1u;
  TFR(17); TFR(29); TFR(16); TFR(24);
  x0 += ks2; x1 += k0 + 2u;
  TFR(13); TFR(15); TFR(26); TFR(6);
  x0 += k0;  x1 += k1 + 3u;
  TFR(17); TFR(29); TFR(16); TFR(24);
  x0 += k1;  x1 += ks2 + 4u;
  TFR(13); TFR(15); TFR(26); TFR(6);
  x0 += ks2; x1 += k0 + 5u;
#undef TFR
  o0 = x0; o1 = x1;
}

__device__ inline float bits_to_uniform(uint32_t bits) {
  float f = __uint_as_float((bits >> 9) | 0x3F800000u) - 1.0f;
  return f < 0.f ? 0.f : f;
}

struct StepKeys { uint32_t k1a[TS], k1b[TS], k2a[TS], k2b[TS]; };

// LDS-only barrier: orders LDS ops without draining global loads/stores (vmcnt).
__device__ inline void bar_lds() {
  asm volatile("s_waitcnt lgkmcnt(0)\n\ts_barrier" ::: "memory");
}

#define ALD(p)     __hip_atomic_load((p),  __ATOMIC_RELAXED, __HIP_MEMORY_SCOPE_AGENT)
#define AST(p, v)  __hip_atomic_store((p), (v), __ATOMIC_RELAXED, __HIP_MEMORY_SCOPE_AGENT)

// flags/cnt live in d_ws (poisoned 0xAA every replay): zeroed before k_fused.
__global__ void k_zero(unsigned* __restrict__ cnt, unsigned* __restrict__ stflag,
                       unsigned* __restrict__ pflag) {
  if (threadIdx.x < TS) {
    cnt[threadIdx.x] = 0u; stflag[threadIdx.x] = 0u; pflag[threadIdx.x] = 0u;
  }
}

__global__ __launch_bounds__(SIMT, 4)
void k_fused(const float* __restrict__ H,
             int* __restrict__ edge_cnt, uint32_t* __restrict__ edge_words,
             unsigned* __restrict__ stbuf, unsigned* __restrict__ stflag,
             unsigned* __restrict__ pflag, unsigned* __restrict__ cntg,
             const float* __restrict__ x,
             const float* __restrict__ beta, const float* __restrict__ gamma_,
             float* __restrict__ out, StepKeys keys) {
  const int tid = threadIdx.x;
  const int bi  = blockIdx.x;

  if (bi >= TS) {
    // ---------- scan role: RPB consecutive rows, rolling PK-deep pipeline ----------
    const int base = (bi - TS) * RPB;
    const int t    = base / EE;          // single t per block (RPB | EE)
    const int e0   = base - t * EE;

    __shared__ int      scnt_arr[RPB];
    __shared__ uint16_t lists[RPB][CAP_E];
    if (tid < RPB) scnt_arr[tid] = 0;

    const float4* h0 = reinterpret_cast<const float4*>(H) + (size_t)base * F4R;
    const bool has2 = tid < F4R - 2048;  // tid < 452

    float4 b0[PK], b1[PK], b2[PK];
#pragma unroll
    for (int p = 0; p < PK; ++p) {       // prologue: PK rows (15 loads) in flight
      const float4* hr = h0 + (size_t)p * F4R;
      b0[p] = hr[tid];
      b1[p] = hr[tid + 1024];
      b2[p] = has2 ? hr[tid + 2048] : make_float4(0.f, 0.f, 0.f, 0.f);
    }
    bar_lds();                           // scnt_arr zeroed visible

#define PROCS(vv, b4, rr) do { \
    if ((vv).x != 0.f) { int q = atomicAdd(&scnt_arr[rr], 1); if (q < CAP_E) lists[rr][q] = (uint16_t)((b4) + 0); } \
    if ((vv).y != 0.f) { int q = atomicAdd(&scnt_arr[rr], 1); if (q < CAP_E) lists[rr][q] = (uint16_t)((b4) + 1); } \
    if ((vv).z != 0.f) { int q = atomicAdd(&scnt_arr[rr], 1); if (q < CAP_E) lists[rr][q] = (uint16_t)((b4) + 2); } \
    if ((vv).w != 0.f) { int q = atomicAdd(&scnt_arr[rr], 1); if (q < CAP_E) lists[rr][q] = (uint16_t)((b4) + 3); } \
  } while (0)

    for (int o = 0; o < RPB / PK; ++o) {
#pragma unroll
      for (int p = 0; p < PK; ++p) {     // static buffer index p: stays in VGPRs
        const int r = o * PK + p;
        float4 va = b0[p], vb = b1[p], vc = b2[p];
        if (o + 1 < RPB / PK) {          // refill row r+PK into slot p (uniform branch)
          const float4* hr = h0 + (size_t)(r + PK) * F4R;
          b0[p] = hr[tid];
          b1[p] = hr[tid + 1024];
          if (has2) b2[p] = hr[tid + 2048];
        }
        PROCS(va, 4 * tid, r);
        PROCS(vb, 4 * (tid + 1024), r);
        if (has2) PROCS(vc, 4 * (tid + 2048), r);
        bar_lds();                       // row r list complete (loads stay in flight)
        // publish row r (runs concurrently with next row's PROC, no extra barrier)
        int c = scnt_arr[r]; c = c < CAP_E ? c : CAP_E;
        const int row = base + r, e = e0 + r;
        if (tid == 0) AST(&edge_cnt[row], c);
        int words = (c + 1) >> 1;
        int wmax = words > PREW ? words : PREW;   // sentinel-pad for sim prefetch
        if (tid < wmax) {
          uint32_t lo = (2 * tid     < c) ? (uint32_t)lists[r][2 * tid]     : 0xFFFFu;
          uint32_t hi = (2 * tid + 1 < c) ? (uint32_t)lists[r][2 * tid + 1] : 0xFFFFu;
          AST(&edge_words[((size_t)t * WPR + tid) * EE + e], lo | (hi << 16));
        }
      }
    }
#undef PROCS
    __syncthreads();  // compiler emits s_waitcnt vmcnt(0): all edge stores at MALL
    if (tid == 0)
      __hip_atomic_fetch_add(&cntg[t], (unsigned)RPB,
                             __ATOMIC_RELAXED, __HIP_MEMORY_SCOPE_AGENT);
    return;
  }

  // ---------------- sim role: block t computes step t ----------------
  const int t = bi;
  __shared__ int      nvst[NN];    // 40 KB: pure two-hop counts (zeroed off-chain)
  __shared__ unsigned st8w[STW];   // 10 KB: per-node state BYTES (0/1/2)
  unsigned char* st8 = (unsigned char*)st8w;

  // 1) off-chain prep: uniforms (threefry), beta/gamma, zero nvst; t=0 init from x.
  float u1r[NPT], u2r[NPT], bet[NPT], gam[NPT], p0a[NPT], p1a[NPT], p2a[NPT];
#pragma unroll
  for (int k = 0; k < NPT; ++k) {
    int n = tid + k * SIMT;
    if (n < NN) {
      uint32_t a, b;
      tf2x32(keys.k1a[t], keys.k1b[t], 0u, (uint32_t)n, a, b);
      u1r[k] = bits_to_uniform(a ^ b);
      tf2x32(keys.k2a[t], keys.k2b[t], 0u, (uint32_t)n, a, b);
      u2r[k] = bits_to_uniform(a ^ b);
      bet[k] = beta[n]; gam[k] = gamma_[n];
      nvst[n] = 0;
    }
  }
  if (t == 0) {
#pragma unroll
    for (int k = 0; k < NPT; ++k) {
      int n = tid + k * SIMT;
      if (n < NN) {
        float x0 = x[n * 3 + 0], x1 = x[n * 3 + 1], x2 = x[n * 3 + 2];
        p0a[k] = x0; p1a[k] = x1; p2a[k] = x2;
        st8[n] = (unsigned char)((x1 == 1.f) ? 1 : ((x0 == 1.f) ? 0 : 2));
        out[n * 3 + 0] = x0; out[n * 3 + 1] = x1; out[n * 3 + 2] = x2;
        out[S_OFF + n * 3 + 0] = x0; out[S_OFF + n * 3 + 1] = x1; out[S_OFF + n * 3 + 2] = x2;
      }
    }
  }

  // 2) edge-data gate (scan producers); prefetch edge words into regs (off-chain).
  if (tid == 0) {
    while (ALD(&cntg[t]) < (unsigned)EE) __builtin_amdgcn_s_sleep(8);
  }
  bar_lds();  // gate seen; also orders nvst zeroing + t=0 st8 init
  int ec = 0; uint32_t w[PREW];
  const uint32_t* wb = edge_words + (size_t)t * WPR * EE + tid;
  if (tid < EE) {
    ec = ALD(&edge_cnt[t * EE + tid]); if (ec > CAP_E) ec = CAP_E;
#pragma unroll
    for (int j = 0; j < PREW; ++j) w[j] = ALD(&wb[(size_t)j * EE]);  // independent
  }

  // 3) state gate: restore st8 from block t-1 (10 KB = 2500 dwords, strided loop)
  if (t > 0) {
    if (tid == 0) {
      while (ALD(&stflag[t - 1]) == 0u) __builtin_amdgcn_s_sleep(1);
    }
    bar_lds();  // flag seen by all
    for (int i = tid; i < STW; i += SIMT)            // 3 iters: FIXED (was tid<STW)
      st8w[i] = ALD(&stbuf[(size_t)(t - 1) * STW + i]);
    bar_lds();  // st8 restored
  }

  // 4) edge phase: s = #infected members (st8 gather); scatter s into nvst counts
  if (tid < EE) {
    int words = (ec + 1) >> 1;
    int s = 0;
#pragma unroll
    for (int j = 0; j < PREW; ++j) {
      uint32_t lo = w[j] & 0xFFFFu, hi = w[j] >> 16;
      if (lo != 0xFFFFu) s += (st8[lo] == 1) ? 1 : 0;
      if (hi != 0xFFFFu) s += (st8[hi] == 1) ? 1 : 0;
    }
    for (int j = PREW; j < words; ++j) {   // rare tail (ec > 16)
      uint32_t ww = ALD(&wb[(size_t)j * EE]);
      uint32_t lo = ww & 0xFFFFu, hi = ww >> 16;
      if (lo != 0xFFFFu) s += (st8[lo] == 1) ? 1 : 0;
      if (hi != 0xFFFFu) s += (st8[hi] == 1) ? 1 : 0;
    }
    if (s > 0) {
#pragma unroll
      for (int j = 0; j < PREW; ++j) {
        uint32_t lo = w[j] & 0xFFFFu, hi = w[j] >> 16;
        if (lo != 0xFFFFu) atomicAdd(&nvst[lo], s);
        if (hi != 0xFFFFu) atomicAdd(&nvst[hi], s);
      }
      for (int j = PREW; j < words; ++j) {
        uint32_t ww = ALD(&wb[(size_t)j * EE]);
        uint32_t lo = ww & 0xFFFFu, hi = ww >> 16;
        if (lo != 0xFFFFu) atomicAdd(&nvst[lo], s);
        if (hi != 0xFFFFu) atomicAdd(&nvst[hi], s);
      }
    }
  }
  bar_lds();  // nvst counts complete

  // 5) p gate: prev p-rows (usually already published while our edge phase ran)
  if (t > 0) {
    if (tid == 0) {
      while (ALD(&pflag[t - 1]) == 0u) __builtin_amdgcn_s_sleep(1);
    }
    bar_lds();
    const float* pp = out + (size_t)t * ROW;
#pragma unroll
    for (int k = 0; k < NPT; ++k) {
      int n = tid + k * SIMT;
      if (n < NN) {
        p0a[k] = ALD(&pp[n * 3 + 0]);
        p1a[k] = ALD(&pp[n * 3 + 1]);
        p2a[k] = ALD(&pp[n * 3 + 2]);
      }
    }
  }

  // 6) node phase: advance p in regs, draw transitions, write NEW state to st8
#pragma unroll
  for (int k = 0; k < NPT; ++k) {
    int n = tid + k * SIMT;
    if (n < NN) {
      int v  = nvst[n];
      int st = (int)st8[n];
      float s1 = (st == 1) ? 1.f : 0.f;
      float new_cases = __fmul_rn(bet[k], (float)v);
      float new_rec   = __fmul_rn(gam[k], s1);
      float q0 = fminf(1.f, fmaxf(0.f, __fsub_rn(p0a[k], new_cases)));
      float q1 = fminf(1.f, fmaxf(0.f, __fsub_rn(__fadd_rn(p1a[k], new_cases), new_rec)));
      float q2 = fminf(1.f, fmaxf(0.f, __fadd_rn(p2a[k], new_rec)));

      bool was_S  = (st == 0);
      bool was_I  = (st == 1);
      bool s_to_I = was_S && (u1r[k] < q1);
      bool i_event = was_I && (u1r[k] < q2);
      bool u2lt   = (u2r[k] < 0.5f);
      bool i_to_R = i_event && u2lt;
      bool i_to_S = i_event && !u2lt;
      bool new_S = (was_S && !s_to_I) || i_to_S;
      bool new_I = s_to_I || (was_I && !i_event);
      // mutually exclusive & exhaustive: state code -> one-hot written later
      int stn = new_I ? 1 : (new_S ? 0 : 2);
      p0a[k] = q0; p1a[k] = q1; p2a[k] = q2;   // hold q in regs for p-publish
      st8[n] = (unsigned char)stn;             // own byte: no race
    }
  }
  bar_lds();  // st8 (new states) complete

  // 7) publish STATE first (tiny drain: 2500 dwords strided), then P, then s-rows
  for (int i = tid; i < STW; i += SIMT)              // FIXED (was tid<STW)
    AST(&stbuf[(size_t)t * STW + i], st8w[i]);
  __syncthreads();                     // drain: stbuf only => fast
  if (tid == 0) AST(&stflag[t], 1u);

  float* po = out + (size_t)(t + 1) * ROW;
#pragma unroll
  for (int k = 0; k < NPT; ++k) {
    int n = tid + k * SIMT;
    if (n < NN) {
      AST(&po[n * 3 + 0], p0a[k]);
      AST(&po[n * 3 + 1], p1a[k]);
      AST(&po[n * 3 + 2], p2a[k]);
    }
  }
  __syncthreads();                     // drain p rows (overlaps consumer's edge phase)
  if (tid == 0) AST(&pflag[t], 1u);

  float* so = out + S_OFF + (size_t)(t + 1) * ROW;   // host-only: fire-and-forget
#pragma unroll
  for (int k = 0; k < NPT; ++k) {
    int n = tid + k * SIMT;
    if (n < NN) {
      int stn = (int)st8[n];
      so[n * 3 + 0] = (stn == 0) ? 1.f : 0.f;
      so[n * 3 + 1] = (stn == 1) ? 1.f : 0.f;
      so[n * 3 + 2] = (stn == 2) ? 1.f : 0.f;
    }
  }
}

extern "C" void kernel_launch(void* const* d_in, const int* in_sizes, int n_in,
                              void* d_out, int out_size, void* d_ws, size_t ws_size,
                              hipStream_t stream) {
  const float* x      = (const float*)d_in[0];
  const float* H      = (const float*)d_in[1];
  const float* beta   = (const float*)d_in[2];
  const float* gamma_ = (const float*)d_in[3];
  float* out = (float*)d_out;

  // key chain: key0 = jax.random.key(42) = (0,42); split(key,3) partitionable:
  // subkey i = threefry(key, (0,i)); carry = subkey 0.
  StepKeys keys;
  uint32_t key0 = 0u, key1 = 42u;
  for (int t = 0; t < TS; ++t) {
    uint32_t a0, b0, a1, b1, a2, b2;
    tf2x32(key0, key1, 0u, 0u, a0, b0);
    tf2x32(key0, key1, 0u, 1u, a1, b1);
    tf2x32(key0, key1, 0u, 2u, a2, b2);
    keys.k1a[t] = a1; keys.k1b[t] = b1; keys.k2a[t] = a2; keys.k2b[t] = b2;
    key0 = a0; key1 = b0;
  }

  // workspace layout (~3.3 MB)
  size_t off = 0;
  auto take = [&](size_t bytes) { size_t o = off; off += (bytes + 255) & ~(size_t)255; return o; };
  size_t o_ec = take((size_t)TS * EE * sizeof(int));
  size_t o_ew = take((size_t)TS * WPR * EE * sizeof(uint32_t));
  size_t o_sb = take((size_t)TS * STW * sizeof(unsigned));
  size_t o_ct = take((size_t)TS * sizeof(unsigned));
  size_t o_fl = take((size_t)TS * sizeof(unsigned));
  size_t o_pf = take((size_t)TS * sizeof(unsigned));

  int*      edge_cnt   = (int*)((char*)d_ws + o_ec);
  uint32_t* edge_words = (uint32_t*)((char*)d_ws + o_ew);
  unsigned* stbuf      = (unsigned*)((char*)d_ws + o_sb);
  unsigned* cnt        = (unsigned*)((char*)d_ws + o_ct);
  unsigned* stflag     = (unsigned*)((char*)d_ws + o_fl);
  unsigned* pflag      = (unsigned*)((char*)d_ws + o_pf);

  k_zero<<<1, 64, 0, stream>>>(cnt, stflag, pflag);
  k_fused<<<TS + SCANB, SIMT, 0, stream>>>(H, edge_cnt, edge_words, stbuf, stflag,
                                           pflag, cnt, x, beta, gamma_, out, keys);
}

// Round 6
// 1695.633 us; speedup vs baseline: 1.1082x; 1.0999x over previous
//
#include <hip/hip_runtime.h>
#include <stdint.h>

// JAX jax_threefry_partitionable=True semantics (verified exact, rounds 1-9).
// Round-16: TWO STREAM-ORDERED KERNELS. R10-R15 post-mortem: every architecture
// (single-CU sim, pipelined per-step blocks, two-flag handoff) lands at k_fused
// ~700-820us because the sim chain runs ~20-24us/step no matter what -- and with
// one CU active, rocprof's device-wide counters can't see why. This round
// isolates it: k_scan (1450 scan blocks + 29 RNG blocks) runs first; the kernel
// boundary is a full barrier + cache flush, so ALL cross-block machinery dies:
// no cnt/stflag/pflag, no polls, no relaxed-agent MALL ops, no vmcnt drains.
// Scan uses plain write-back stores; sim uses plain L2-cached loads (~200ns vs
// ~1us MALL RTT per burst). k_sim: one block, 29 steps, 2 LDS-only barriers per
// step, edge-words + uniforms for t+1 prefetched into registers during node
// phase t. rocprof now reports scan and sim separately.
constexpr int NN = 10000;          // nodes
constexpr int EE = 1000;           // hyperedges
constexpr int TT = 30;             // output rows
constexpr int TS = TT - 1;         // simulated steps
constexpr int ROW = NN * 3;        // floats per output row
constexpr int S_OFF = TT * ROW;    // state section offset in d_out
constexpr int CAP_E = 48;          // max nodes per edge (P(>=48) ~ 1e-30)
constexpr int WPR = CAP_E / 2;     // packed uint32 words per edge row
constexpr int PREW = 8;            // words prefetched unconditionally (covers ec<=16, ~97%)
constexpr int SIMT = 1024;         // block size (16 waves)
constexpr int NPT  = 10;           // nodes per thread, strided mapping n = tid + k*SIMT
constexpr int NROWS = TS * EE;     // 29000 total H rows
constexpr int F4R   = NN / 4;      // 2500 float4 per row
constexpr int RPB   = 20;          // H rows per scan block (divides EE)
constexpr int PK    = 5;           // register pipeline depth in rows
constexpr int SCANB = NROWS / RPB; // 1450 scan blocks
static_assert(EE % RPB == 0 && NROWS % RPB == 0 && RPB % PK == 0, "geometry");

// ---- Threefry-2x32, 20 rounds (exact JAX semantics), host+device ----
__host__ __device__ inline void tf2x32(uint32_t k0, uint32_t k1,
                                       uint32_t x0, uint32_t x1,
                                       uint32_t &o0, uint32_t &o1) {
  uint32_t ks2 = k0 ^ k1 ^ 0x1BD11BDAu;
  x0 += k0; x1 += k1;
#define TFR(r) do { x0 += x1; x1 = (x1 << (r)) | (x1 >> (32 - (r))); x1 ^= x0; } while (0)
  TFR(13); TFR(15); TFR(26); TFR(6);
  x0 += k1;  x1 += ks2 + 1u;
  TFR(17); TFR(29); TFR(16); TFR(24);
  x0 += ks2; x1 += k0 + 2u;
  TFR(13); TFR(15); TFR(26); TFR(6);
  x0 += k0;  x1 += k1 + 3u;
  TFR(17); TFR(29); TFR(16); TFR(24);
  x0 += k1;  x1 += ks2 + 4u;
  TFR(13); TFR(15); TFR(26); TFR(6);
  x0 += ks2; x1 += k0 + 5u;
#undef TFR
  o0 = x0; o1 = x1;
}

__device__ inline float bits_to_uniform(uint32_t bits) {
  float f = __uint_as_float((bits >> 9) | 0x3F800000u) - 1.0f;
  return f < 0.f ? 0.f : f;
}

struct StepKeys { uint32_t k1a[TS], k1b[TS], k2a[TS], k2b[TS]; };

// LDS-only barrier: orders LDS ops without draining global loads/stores (vmcnt).
__device__ inline void bar_lds() {
  asm volatile("s_waitcnt lgkmcnt(0)\n\ts_barrier" ::: "memory");
}

// ================= kernel 1: scan (H row -> edge lists) + RNG =================
__global__ __launch_bounds__(SIMT)
void k_scan(const float* __restrict__ H,
            int* __restrict__ edge_cnt, uint32_t* __restrict__ edge_words,
            unsigned long long* __restrict__ uv, StepKeys keys) {
  const int tid = threadIdx.x;
  const int bi  = blockIdx.x;

  if (bi >= SCANB) {
    // ---- RNG role: block computes step t's uniforms (plain stores) ----
    const int t = bi - SCANB;
#pragma unroll
    for (int k = 0; k < NPT; ++k) {
      int n = tid + k * SIMT;
      if (n < NN) {
        uint32_t a, b;
        tf2x32(keys.k1a[t], keys.k1b[t], 0u, (uint32_t)n, a, b);
        uint32_t b1 = __float_as_uint(bits_to_uniform(a ^ b));
        tf2x32(keys.k2a[t], keys.k2b[t], 0u, (uint32_t)n, a, b);
        uint32_t b2 = __float_as_uint(bits_to_uniform(a ^ b));
        uv[(size_t)t * NN + n] = (unsigned long long)b1 | ((unsigned long long)b2 << 32);
      }
    }
    return;
  }

  // ---- scan role: RPB consecutive rows, rolling PK-deep register pipeline ----
  const int base = bi * RPB;
  const int t    = base / EE;          // single t per block (RPB | EE)
  const int e0   = base - t * EE;

  __shared__ int      scnt_arr[RPB];
  __shared__ uint16_t lists[RPB][CAP_E];
  if (tid < RPB) scnt_arr[tid] = 0;

  const float4* h0 = reinterpret_cast<const float4*>(H) + (size_t)base * F4R;
  const bool has2 = tid < F4R - 2048;  // tid < 452

  float4 b0[PK], b1[PK], b2[PK];
#pragma unroll
  for (int p = 0; p < PK; ++p) {       // prologue: PK rows (15 loads) in flight
    const float4* hr = h0 + (size_t)p * F4R;
    b0[p] = hr[tid];
    b1[p] = hr[tid + 1024];
    b2[p] = has2 ? hr[tid + 2048] : make_float4(0.f, 0.f, 0.f, 0.f);
  }
  bar_lds();                           // scnt_arr zeroed visible

#define PROCS(vv, b4, rr) do { \
  if ((vv).x != 0.f) { int q = atomicAdd(&scnt_arr[rr], 1); if (q < CAP_E) lists[rr][q] = (uint16_t)((b4) + 0); } \
  if ((vv).y != 0.f) { int q = atomicAdd(&scnt_arr[rr], 1); if (q < CAP_E) lists[rr][q] = (uint16_t)((b4) + 1); } \
  if ((vv).z != 0.f) { int q = atomicAdd(&scnt_arr[rr], 1); if (q < CAP_E) lists[rr][q] = (uint16_t)((b4) + 2); } \
  if ((vv).w != 0.f) { int q = atomicAdd(&scnt_arr[rr], 1); if (q < CAP_E) lists[rr][q] = (uint16_t)((b4) + 3); } \
} while (0)

  for (int o = 0; o < RPB / PK; ++o) {
#pragma unroll
    for (int p = 0; p < PK; ++p) {     // static buffer index p: stays in VGPRs
      const int r = o * PK + p;
      float4 va = b0[p], vb = b1[p], vc = b2[p];
      if (o + 1 < RPB / PK) {          // refill row r+PK into slot p (uniform branch)
        const float4* hr = h0 + (size_t)(r + PK) * F4R;
        b0[p] = hr[tid];
        b1[p] = hr[tid + 1024];
        if (has2) b2[p] = hr[tid + 2048];
      }
      PROCS(va, 4 * tid, r);
      PROCS(vb, 4 * (tid + 1024), r);
      if (has2) PROCS(vc, 4 * (tid + 2048), r);
      bar_lds();                       // row r list complete (loads stay in flight)
      // publish row r with PLAIN stores (kernel-end flush provides visibility)
      int c = scnt_arr[r]; c = c < CAP_E ? c : CAP_E;
      const int row = base + r, e = e0 + r;
      if (tid == 0) edge_cnt[row] = c;
      int words = (c + 1) >> 1;
      int wmax = words > PREW ? words : PREW;   // sentinel-pad for sim prefetch
      if (tid < wmax) {
        uint32_t lo = (2 * tid     < c) ? (uint32_t)lists[r][2 * tid]     : 0xFFFFu;
        uint32_t hi = (2 * tid + 1 < c) ? (uint32_t)lists[r][2 * tid + 1] : 0xFFFFu;
        edge_words[((size_t)t * WPR + tid) * EE + e] = lo | (hi << 16);
      }
    }
  }
#undef PROCS
  // no drain, no flags: kernel boundary is the barrier
}

// ================= kernel 2: sim (one block, 29 serial steps) =================
__global__ __launch_bounds__(SIMT, 4)
void k_sim(const int* __restrict__ edge_cnt, const uint32_t* __restrict__ edge_words,
           const unsigned long long* __restrict__ uv,
           const float* __restrict__ x,
           const float* __restrict__ beta, const float* __restrict__ gamma_,
           float* __restrict__ out) {
  const int tid = threadIdx.x;
  __shared__ int nvst[NN];             // 40 KB: two-hop counts only
  __shared__ unsigned char st8[NN];    // 10 KB: per-node state bytes (0/1/2)

  // init: p/state from x, write row 0 of both sections, zero counts
  float p0a[NPT], p1a[NPT], p2a[NPT], bet[NPT], gam[NPT];
#pragma unroll
  for (int k = 0; k < NPT; ++k) {
    int n = tid + k * SIMT;
    if (n < NN) {
      float x0 = x[n * 3 + 0], x1 = x[n * 3 + 1], x2 = x[n * 3 + 2];
      p0a[k] = x0; p1a[k] = x1; p2a[k] = x2;
      st8[n] = (unsigned char)((x1 == 1.f) ? 1 : ((x0 == 1.f) ? 0 : 2));
      nvst[n] = 0;
      bet[k] = beta[n]; gam[k] = gamma_[n];
      out[n * 3 + 0] = x0; out[n * 3 + 1] = x1; out[n * 3 + 2] = x2;
      out[S_OFF + n * 3 + 0] = x0; out[S_OFF + n * 3 + 1] = x1; out[S_OFF + n * 3 + 2] = x2;
    }
  }

  // prologue prefetch: edge data + uniforms for t=0 (one exposed L2 RTT)
  int ec = 0; uint32_t w[PREW];
  float u1r[NPT], u2r[NPT];
  if (tid < EE) {
    ec = edge_cnt[tid]; if (ec > CAP_E) ec = CAP_E;
#pragma unroll
    for (int j = 0; j < PREW; ++j) w[j] = edge_words[((size_t)0 * WPR + j) * EE + tid];
  }
#pragma unroll
  for (int k = 0; k < NPT; ++k) {
    int n = tid + k * SIMT;
    if (n < NN) {
      unsigned long long raw = uv[n];
      u1r[k] = __uint_as_float((uint32_t)raw);
      u2r[k] = __uint_as_float((uint32_t)(raw >> 32));
    }
  }
  bar_lds();   // st8/nvst init visible

  for (int t = 0; t < TS; ++t) {
    // ---- edge phase: s = #infected members; scatter s into nvst counts ----
    if (tid < EE) {
      const uint32_t* wb = edge_words + (size_t)t * WPR * EE + tid;
      int words = (ec + 1) >> 1;
      int s = 0;
#pragma unroll
      for (int j = 0; j < PREW; ++j) {
        uint32_t lo = w[j] & 0xFFFFu, hi = w[j] >> 16;
        if (lo != 0xFFFFu) s += (st8[lo] == 1) ? 1 : 0;
        if (hi != 0xFFFFu) s += (st8[hi] == 1) ? 1 : 0;
      }
      for (int j = PREW; j < words; ++j) {   // rare tail (ec > 16)
        uint32_t ww = wb[(size_t)j * EE];
        uint32_t lo = ww & 0xFFFFu, hi = ww >> 16;
        if (lo != 0xFFFFu) s += (st8[lo] == 1) ? 1 : 0;
        if (hi != 0xFFFFu) s += (st8[hi] == 1) ? 1 : 0;
      }
      if (s > 0) {
#pragma unroll
        for (int j = 0; j < PREW; ++j) {
          uint32_t lo = w[j] & 0xFFFFu, hi = w[j] >> 16;
          if (lo != 0xFFFFu) atomicAdd(&nvst[lo], s);
          if (hi != 0xFFFFu) atomicAdd(&nvst[hi], s);
        }
        for (int j = PREW; j < words; ++j) {
          uint32_t ww = wb[(size_t)j * EE];
          uint32_t lo = ww & 0xFFFFu, hi = ww >> 16;
          if (lo != 0xFFFFu) atomicAdd(&nvst[lo], s);
          if (hi != 0xFFFFu) atomicAdd(&nvst[hi], s);
        }
      }
    }
    bar_lds();  // nvst counts complete

    // ---- prefetch t+1 edge data into regs (hidden under node phase) ----
    int ecn = 0; uint32_t wn[PREW];
    {
      const int tn = (t + 1 < TS) ? t + 1 : t;
      if (tid < EE) {
        ecn = edge_cnt[tn * EE + tid]; if (ecn > CAP_E) ecn = CAP_E;
#pragma unroll
        for (int j = 0; j < PREW; ++j) wn[j] = edge_words[((size_t)tn * WPR + j) * EE + tid];
      }
    }

    // ---- node phase: advance p, draw transitions, write rows, update st8 ----
    float* po = out + (size_t)(t + 1) * ROW;
    float* so = out + S_OFF + (size_t)(t + 1) * ROW;
#pragma unroll
    for (int k = 0; k < NPT; ++k) {
      int n = tid + k * SIMT;
      if (n < NN) {
        int v  = nvst[n];
        int st = (int)st8[n];
        float s1 = (st == 1) ? 1.f : 0.f;
        float new_cases = __fmul_rn(bet[k], (float)v);
        float new_rec   = __fmul_rn(gam[k], s1);
        float q0 = fminf(1.f, fmaxf(0.f, __fsub_rn(p0a[k], new_cases)));
        float q1 = fminf(1.f, fmaxf(0.f, __fsub_rn(__fadd_rn(p1a[k], new_cases), new_rec)));
        float q2 = fminf(1.f, fmaxf(0.f, __fadd_rn(p2a[k], new_rec)));
        p0a[k] = q0; p1a[k] = q1; p2a[k] = q2;

        bool was_S  = (st == 0);
        bool was_I  = (st == 1);
        bool s_to_I = was_S && (u1r[k] < q1);
        bool i_event = was_I && (u1r[k] < q2);
        bool u2lt   = (u2r[k] < 0.5f);
        bool i_to_R = i_event && u2lt;
        bool i_to_S = i_event && !u2lt;
        bool new_S = (was_S && !s_to_I) || i_to_S;
        bool new_I = s_to_I || (was_I && !i_event);
        bool new_R = (!was_S && !was_I) || i_to_R;

        po[n * 3 + 0] = q0; po[n * 3 + 1] = q1; po[n * 3 + 2] = q2;
        so[n * 3 + 0] = new_S ? 1.f : 0.f;
        so[n * 3 + 1] = new_I ? 1.f : 0.f;
        so[n * 3 + 2] = new_R ? 1.f : 0.f;
        st8[n] = (unsigned char)(new_I ? 1 : (new_S ? 0 : 2));
        nvst[n] = 0;                     // reset count for next step
      }
    }

    // ---- prefetch t+1 uniforms (consumed next node phase; hidden) ----
    if (t + 1 < TS) {
#pragma unroll
      for (int k = 0; k < NPT; ++k) {
        int n = tid + k * SIMT;
        if (n < NN) {
          unsigned long long raw = uv[(size_t)(t + 1) * NN + n];
          u1r[k] = __uint_as_float((uint32_t)raw);
          u2r[k] = __uint_as_float((uint32_t)(raw >> 32));
        }
      }
    }
    bar_lds();  // st8 update complete before next edge phase

    ec = ecn;
#pragma unroll
    for (int j = 0; j < PREW; ++j) w[j] = wn[j];
  }
}

extern "C" void kernel_launch(void* const* d_in, const int* in_sizes, int n_in,
                              void* d_out, int out_size, void* d_ws, size_t ws_size,
                              hipStream_t stream) {
  const float* x      = (const float*)d_in[0];
  const float* H      = (const float*)d_in[1];
  const float* beta   = (const float*)d_in[2];
  const float* gamma_ = (const float*)d_in[3];
  float* out = (float*)d_out;

  // key chain: key0 = jax.random.key(42) = (0,42); split(key,3) partitionable:
  // subkey i = threefry(key, (0,i)); carry = subkey 0.
  StepKeys keys;
  uint32_t key0 = 0u, key1 = 42u;
  for (int t = 0; t < TS; ++t) {
    uint32_t a0, b0, a1, b1, a2, b2;
    tf2x32(key0, key1, 0u, 0u, a0, b0);
    tf2x32(key0, key1, 0u, 1u, a1, b1);
    tf2x32(key0, key1, 0u, 2u, a2, b2);
    keys.k1a[t] = a1; keys.k1b[t] = b1; keys.k2a[t] = a2; keys.k2b[t] = b2;
    key0 = a0; key1 = b0;
  }

  // workspace layout (~5.2 MB); everything read is written by k_scan first,
  // so the harness poison is harmless and no zeroing kernel is needed.
  size_t off = 0;
  auto take = [&](size_t bytes) { size_t o = off; off += (bytes + 255) & ~(size_t)255; return o; };
  size_t o_ec = take((size_t)NROWS * sizeof(int));
  size_t o_ew = take((size_t)TS * WPR * EE * sizeof(uint32_t));
  size_t o_uv = take((size_t)TS * NN * sizeof(unsigned long long));

  int*      edge_cnt   = (int*)((char*)d_ws + o_ec);
  uint32_t* edge_words = (uint32_t*)((char*)d_ws + o_ew);
  unsigned long long* uvp = (unsigned long long*)((char*)d_ws + o_uv);

  k_scan<<<SCANB + TS, SIMT, 0, stream>>>(H, edge_cnt, edge_words, uvp, keys);
  k_sim<<<1, SIMT, 0, stream>>>(edge_cnt, edge_words, uvp, x, beta, gamma_, out);
}

// Round 7
// 1692.651 us; speedup vs baseline: 1.1102x; 1.0018x over previous
//
#include <hip/hip_runtime.h>
#include <stdint.h>

// JAX jax_threefry_partitionable=True semantics (verified exact, rounds 1-9).
// Round-17: recombine the measured-best parts. Accounting across R10-R16 (fill
// ~740us + ~320us fixed small-dispatch overhead per replay) gives kernel times:
// R11 fused=420 (BEST, sim fully hidden under scan), R16 split scan+sim=635
// (scan ~250-300 with the RPB=20 rolling pipeline, sim ~350-400 alone). So:
// fuse R16's scan (fastest scan) with R16's sim structure (cleanest chain),
// using the R10-R15-proven AST/fetch_add/ALD MALL protocol for cross-block
// visibility. RNG blocks are dispatched FIRST (blocks 1..29) so uv is ready
// immediately; each RNG block +1s cnt[t], scan blocks +20 => gate EE+1.
// Sim polls cnt[t+1] between edge and node phases (scan runs ~10 steps ahead
// => instant), prefetches t+1 edge words before node phase and t+1 uniforms
// after their last use. p stays in block-0 registers; out rows are plain
// fire-and-forget stores (host-only). No stbuf/pflag/state handoff.
constexpr int NN = 10000;          // nodes
constexpr int EE = 1000;           // hyperedges
constexpr int TT = 30;             // output rows
constexpr int TS = TT - 1;         // simulated steps
constexpr int ROW = NN * 3;        // floats per output row
constexpr int S_OFF = TT * ROW;    // state section offset in d_out
constexpr int CAP_E = 48;          // max nodes per edge (P(>=48) ~ 1e-30)
constexpr int WPR = CAP_E / 2;     // packed uint32 words per edge row
constexpr int PREW = 8;            // words prefetched unconditionally (covers ec<=16, ~97%)
constexpr int SIMT = 1024;         // block size (16 waves)
constexpr int NPT  = 10;           // nodes per thread, strided mapping n = tid + k*SIMT
constexpr int NROWS = TS * EE;     // 29000 total H rows
constexpr int F4R   = NN / 4;      // 2500 float4 per row
constexpr int RPB   = 20;          // H rows per scan block (divides EE => one t/block)
constexpr int PK    = 5;           // register pipeline depth in rows
constexpr int SCANB = NROWS / RPB; // 1450 scan blocks
constexpr unsigned GATE = EE + 1;  // scan 1000 rows + 1 RNG block per step
static_assert(EE % RPB == 0 && NROWS % RPB == 0 && RPB % PK == 0, "geometry");

// ---- Threefry-2x32, 20 rounds (exact JAX semantics), host+device ----
__host__ __device__ inline void tf2x32(uint32_t k0, uint32_t k1,
                                       uint32_t x0, uint32_t x1,
                                       uint32_t &o0, uint32_t &o1) {
  uint32_t ks2 = k0 ^ k1 ^ 0x1BD11BDAu;
  x0 += k0; x1 += k1;
#define TFR(r) do { x0 += x1; x1 = (x1 << (r)) | (x1 >> (32 - (r))); x1 ^= x0; } while (0)
  TFR(13); TFR(15); TFR(26); TFR(6);
  x0 += k1;  x1 += ks2 + 1u;
  TFR(17); TFR(29); TFR(16); TFR(24);
  x0 += ks2; x1 += k0 + 2u;
  TFR(13); TFR(15); TFR(26); TFR(6);
  x0 += k0;  x1 += k1 + 3u;
  TFR(17); TFR(29); TFR(16); TFR(24);
  x0 += k1;  x1 += ks2 + 4u;
  TFR(13); TFR(15); TFR(26); TFR(6);
  x0 += ks2; x1 += k0 + 5u;
#undef TFR
  o0 = x0; o1 = x1;
}

__device__ inline float bits_to_uniform(uint32_t bits) {
  float f = __uint_as_float((bits >> 9) | 0x3F800000u) - 1.0f;
  return f < 0.f ? 0.f : f;
}

struct StepKeys { uint32_t k1a[TS], k1b[TS], k2a[TS], k2b[TS]; };

// LDS-only barrier: orders LDS ops without draining global loads/stores (vmcnt).
__device__ inline void bar_lds() {
  asm volatile("s_waitcnt lgkmcnt(0)\n\ts_barrier" ::: "memory");
}

#define ALD(p)     __hip_atomic_load((p),  __ATOMIC_RELAXED, __HIP_MEMORY_SCOPE_AGENT)
#define AST(p, v)  __hip_atomic_store((p), (v), __ATOMIC_RELAXED, __HIP_MEMORY_SCOPE_AGENT)

// cnt lives in d_ws (poisoned 0xAA every replay): zeroed before k_fused.
__global__ void k_zero(unsigned* __restrict__ cnt) {
  if (threadIdx.x < TS) cnt[threadIdx.x] = 0u;
}

__global__ __launch_bounds__(SIMT, 4)
void k_fused(const float* __restrict__ H,
             int* __restrict__ edge_cnt, uint32_t* __restrict__ edge_words,
             unsigned long long* __restrict__ uv, unsigned* __restrict__ cntg,
             const float* __restrict__ x,
             const float* __restrict__ beta, const float* __restrict__ gamma_,
             float* __restrict__ out, StepKeys keys) {
  const int tid = threadIdx.x;
  const int bi  = blockIdx.x;

  if (bi >= 1 && bi <= TS) {
    // ---- RNG role (dispatched early): step t uniforms -> uv, then +1 cnt[t] ----
    const int t = bi - 1;
#pragma unroll
    for (int k = 0; k < NPT; ++k) {
      int n = tid + k * SIMT;
      if (n < NN) {
        uint32_t a, b;
        tf2x32(keys.k1a[t], keys.k1b[t], 0u, (uint32_t)n, a, b);
        uint32_t b1 = __float_as_uint(bits_to_uniform(a ^ b));
        tf2x32(keys.k2a[t], keys.k2b[t], 0u, (uint32_t)n, a, b);
        uint32_t b2 = __float_as_uint(bits_to_uniform(a ^ b));
        unsigned long long raw = (unsigned long long)b1 | ((unsigned long long)b2 << 32);
        AST(&uv[(size_t)t * NN + n], raw);
      }
    }
    __syncthreads();  // s_waitcnt vmcnt(0): uv stores at MALL
    if (tid == 0)
      __hip_atomic_fetch_add(&cntg[t], 1u, __ATOMIC_RELAXED, __HIP_MEMORY_SCOPE_AGENT);
    return;
  }

  if (bi > TS) {
    // ---- scan role: RPB consecutive rows, rolling PK-deep register pipeline ----
    const int base = (bi - 1 - TS) * RPB;
    const int t    = base / EE;          // single t per block (RPB | EE)
    const int e0   = base - t * EE;

    __shared__ int      scnt_arr[RPB];
    __shared__ uint16_t lists[RPB][CAP_E];
    if (tid < RPB) scnt_arr[tid] = 0;

    const float4* h0 = reinterpret_cast<const float4*>(H) + (size_t)base * F4R;
    const bool has2 = tid < F4R - 2048;  // tid < 452

    float4 b0[PK], b1[PK], b2[PK];
#pragma unroll
    for (int p = 0; p < PK; ++p) {       // prologue: PK rows (15 loads) in flight
      const float4* hr = h0 + (size_t)p * F4R;
      b0[p] = hr[tid];
      b1[p] = hr[tid + 1024];
      b2[p] = has2 ? hr[tid + 2048] : make_float4(0.f, 0.f, 0.f, 0.f);
    }
    bar_lds();                           // scnt_arr zeroed visible

#define PROCS(vv, b4, rr) do { \
    if ((vv).x != 0.f) { int q = atomicAdd(&scnt_arr[rr], 1); if (q < CAP_E) lists[rr][q] = (uint16_t)((b4) + 0); } \
    if ((vv).y != 0.f) { int q = atomicAdd(&scnt_arr[rr], 1); if (q < CAP_E) lists[rr][q] = (uint16_t)((b4) + 1); } \
    if ((vv).z != 0.f) { int q = atomicAdd(&scnt_arr[rr], 1); if (q < CAP_E) lists[rr][q] = (uint16_t)((b4) + 2); } \
    if ((vv).w != 0.f) { int q = atomicAdd(&scnt_arr[rr], 1); if (q < CAP_E) lists[rr][q] = (uint16_t)((b4) + 3); } \
  } while (0)

    for (int o = 0; o < RPB / PK; ++o) {
#pragma unroll
      for (int p = 0; p < PK; ++p) {     // static buffer index p: stays in VGPRs
        const int r = o * PK + p;
        float4 va = b0[p], vb = b1[p], vc = b2[p];
        if (o + 1 < RPB / PK) {          // refill row r+PK into slot p (uniform branch)
          const float4* hr = h0 + (size_t)(r + PK) * F4R;
          b0[p] = hr[tid];
          b1[p] = hr[tid + 1024];
          if (has2) b2[p] = hr[tid + 2048];
        }
        PROCS(va, 4 * tid, r);
        PROCS(vb, 4 * (tid + 1024), r);
        if (has2) PROCS(vc, 4 * (tid + 2048), r);
        bar_lds();                       // row r list complete (loads stay in flight)
        // publish row r via AST (MALL write-through); drained once at block end
        int c = scnt_arr[r]; c = c < CAP_E ? c : CAP_E;
        const int row = base + r, e = e0 + r;
        if (tid == 0) AST(&edge_cnt[row], c);
        int words = (c + 1) >> 1;
        int wmax = words > PREW ? words : PREW;   // sentinel-pad for sim prefetch
        if (tid < wmax) {
          uint32_t lo = (2 * tid     < c) ? (uint32_t)lists[r][2 * tid]     : 0xFFFFu;
          uint32_t hi = (2 * tid + 1 < c) ? (uint32_t)lists[r][2 * tid + 1] : 0xFFFFu;
          AST(&edge_words[((size_t)t * WPR + tid) * EE + e], lo | (hi << 16));
        }
      }
    }
#undef PROCS
    __syncthreads();  // s_waitcnt vmcnt(0): all edge stores at MALL
    if (tid == 0)
      __hip_atomic_fetch_add(&cntg[t], (unsigned)RPB,
                             __ATOMIC_RELAXED, __HIP_MEMORY_SCOPE_AGENT);
    return;
  }

  // ---------------- sim role (block 0): 29 serial steps ----------------
  __shared__ int nvst[NN];             // 40 KB: two-hop counts only
  __shared__ unsigned char st8[NN];    // 10 KB: per-node state bytes (0/1/2)

  // init: p/state from x, row 0 of both sections, zero counts (all off-chain)
  float p0a[NPT], p1a[NPT], p2a[NPT], bet[NPT], gam[NPT], u1r[NPT], u2r[NPT];
#pragma unroll
  for (int k = 0; k < NPT; ++k) {
    int n = tid + k * SIMT;
    if (n < NN) {
      float x0 = x[n * 3 + 0], x1 = x[n * 3 + 1], x2 = x[n * 3 + 2];
      p0a[k] = x0; p1a[k] = x1; p2a[k] = x2;
      st8[n] = (unsigned char)((x1 == 1.f) ? 1 : ((x0 == 1.f) ? 0 : 2));
      nvst[n] = 0;
      bet[k] = beta[n]; gam[k] = gamma_[n];
      out[n * 3 + 0] = x0; out[n * 3 + 1] = x1; out[n * 3 + 2] = x2;
      out[S_OFF + n * 3 + 0] = x0; out[S_OFF + n * 3 + 1] = x1; out[S_OFF + n * 3 + 2] = x2;
    }
  }
  bar_lds();   // st8/nvst init visible

  // prologue: gate step 0, then prefetch edge data + uniforms for t=0
  if (tid == 0) {
    while (ALD(&cntg[0]) < GATE) __builtin_amdgcn_s_sleep(1);
  }
  bar_lds();
  int ec = 0; uint32_t w[PREW];
  if (tid < EE) {
    ec = ALD(&edge_cnt[tid]); if (ec > CAP_E) ec = CAP_E;
#pragma unroll
    for (int j = 0; j < PREW; ++j) w[j] = ALD(&edge_words[(size_t)j * EE + tid]);
  }
#pragma unroll
  for (int k = 0; k < NPT; ++k) {
    int n = tid + k * SIMT;
    if (n < NN) {
      unsigned long long raw = ALD(&uv[n]);
      u1r[k] = __uint_as_float((uint32_t)raw);
      u2r[k] = __uint_as_float((uint32_t)(raw >> 32));
    }
  }

  for (int t = 0; t < TS; ++t) {
    // ---- edge phase: s = #infected members; scatter s into nvst counts ----
    if (tid < EE) {
      const uint32_t* wb = edge_words + (size_t)t * WPR * EE + tid;
      int words = (ec + 1) >> 1;
      int s = 0;
#pragma unroll
      for (int j = 0; j < PREW; ++j) {
        uint32_t lo = w[j] & 0xFFFFu, hi = w[j] >> 16;
        if (lo != 0xFFFFu) s += (st8[lo] == 1) ? 1 : 0;
        if (hi != 0xFFFFu) s += (st8[hi] == 1) ? 1 : 0;
      }
      for (int j = PREW; j < words; ++j) {   // rare tail (ec > 16)
        uint32_t ww = ALD(&wb[(size_t)j * EE]);
        uint32_t lo = ww & 0xFFFFu, hi = ww >> 16;
        if (lo != 0xFFFFu) s += (st8[lo] == 1) ? 1 : 0;
        if (hi != 0xFFFFu) s += (st8[hi] == 1) ? 1 : 0;
      }
      if (s > 0) {
#pragma unroll
        for (int j = 0; j < PREW; ++j) {
          uint32_t lo = w[j] & 0xFFFFu, hi = w[j] >> 16;
          if (lo != 0xFFFFu) atomicAdd(&nvst[lo], s);
          if (hi != 0xFFFFu) atomicAdd(&nvst[hi], s);
        }
        for (int j = PREW; j < words; ++j) {
          uint32_t ww = ALD(&wb[(size_t)j * EE]);
          uint32_t lo = ww & 0xFFFFu, hi = ww >> 16;
          if (lo != 0xFFFFu) atomicAdd(&nvst[lo], s);
          if (hi != 0xFFFFu) atomicAdd(&nvst[hi], s);
        }
      }
    }
    bar_lds();  // nvst counts complete; st8 reads done

    // ---- gate + prefetch t+1 edge data (hidden under node phase) ----
    const bool more = (t + 1 < TS);
    if (more && tid == 0) {
      while (ALD(&cntg[t + 1]) < GATE) __builtin_amdgcn_s_sleep(1);
    }
    bar_lds();  // gate seen by all (scan runs ahead: usually instant)
    int ecn = 0; uint32_t wn[PREW];
    if (more && tid < EE) {
      ecn = ALD(&edge_cnt[(t + 1) * EE + tid]); if (ecn > CAP_E) ecn = CAP_E;
#pragma unroll
      for (int j = 0; j < PREW; ++j)
        wn[j] = ALD(&edge_words[((size_t)(t + 1) * WPR + j) * EE + tid]);
    }

    // ---- node phase: advance p, draw transitions, write rows, update st8 ----
    float* po = out + (size_t)(t + 1) * ROW;
    float* so = out + S_OFF + (size_t)(t + 1) * ROW;
#pragma unroll
    for (int k = 0; k < NPT; ++k) {
      int n = tid + k * SIMT;
      if (n < NN) {
        int v  = nvst[n];
        int st = (int)st8[n];
        float s1 = (st == 1) ? 1.f : 0.f;
        float new_cases = __fmul_rn(bet[k], (float)v);
        float new_rec   = __fmul_rn(gam[k], s1);
        float q0 = fminf(1.f, fmaxf(0.f, __fsub_rn(p0a[k], new_cases)));
        float q1 = fminf(1.f, fmaxf(0.f, __fsub_rn(__fadd_rn(p1a[k], new_cases), new_rec)));
        float q2 = fminf(1.f, fmaxf(0.f, __fadd_rn(p2a[k], new_rec)));
        p0a[k] = q0; p1a[k] = q1; p2a[k] = q2;

        bool was_S  = (st == 0);
        bool was_I  = (st == 1);
        bool s_to_I = was_S && (u1r[k] < q1);
        bool i_event = was_I && (u1r[k] < q2);
        bool u2lt   = (u2r[k] < 0.5f);
        bool i_to_R = i_event && u2lt;
        bool i_to_S = i_event && !u2lt;
        bool new_S = (was_S && !s_to_I) || i_to_S;
        bool new_I = s_to_I || (was_I && !i_event);
        bool new_R = (!was_S && !was_I) || i_to_R;

        po[n * 3 + 0] = q0; po[n * 3 + 1] = q1; po[n * 3 + 2] = q2;
        so[n * 3 + 0] = new_S ? 1.f : 0.f;
        so[n * 3 + 1] = new_I ? 1.f : 0.f;
        so[n * 3 + 2] = new_R ? 1.f : 0.f;
        st8[n] = (unsigned char)(new_I ? 1 : (new_S ? 0 : 2));
        nvst[n] = 0;                     // reset count for next step
      }
    }

    // ---- prefetch t+1 uniforms after last u1r/u2r use (hidden) ----
    if (more) {
#pragma unroll
      for (int k = 0; k < NPT; ++k) {
        int n = tid + k * SIMT;
        if (n < NN) {
          unsigned long long raw = ALD(&uv[(size_t)(t + 1) * NN + n]);
          u1r[k] = __uint_as_float((uint32_t)raw);
          u2r[k] = __uint_as_float((uint32_t)(raw >> 32));
        }
      }
      ec = ecn;
#pragma unroll
      for (int j = 0; j < PREW; ++j) w[j] = wn[j];
    }
    bar_lds();  // st8 update complete before next edge phase
  }
}

extern "C" void kernel_launch(void* const* d_in, const int* in_sizes, int n_in,
                              void* d_out, int out_size, void* d_ws, size_t ws_size,
                              hipStream_t stream) {
  const float* x      = (const float*)d_in[0];
  const float* H      = (const float*)d_in[1];
  const float* beta   = (const float*)d_in[2];
  const float* gamma_ = (const float*)d_in[3];
  float* out = (float*)d_out;

  // key chain: key0 = jax.random.key(42) = (0,42); split(key,3) partitionable:
  // subkey i = threefry(key, (0,i)); carry = subkey 0.
  StepKeys keys;
  uint32_t key0 = 0u, key1 = 42u;
  for (int t = 0; t < TS; ++t) {
    uint32_t a0, b0, a1, b1, a2, b2;
    tf2x32(key0, key1, 0u, 0u, a0, b0);
    tf2x32(key0, key1, 0u, 1u, a1, b1);
    tf2x32(key0, key1, 0u, 2u, a2, b2);
    keys.k1a[t] = a1; keys.k1b[t] = b1; keys.k2a[t] = a2; keys.k2b[t] = b2;
    key0 = a0; key1 = b0;
  }

  // workspace layout (~5.3 MB)
  size_t off = 0;
  auto take = [&](size_t bytes) { size_t o = off; off += (bytes + 255) & ~(size_t)255; return o; };
  size_t o_ec = take((size_t)NROWS * sizeof(int));
  size_t o_ew = take((size_t)TS * WPR * EE * sizeof(uint32_t));
  size_t o_uv = take((size_t)TS * NN * sizeof(unsigned long long));
  size_t o_ct = take((size_t)TS * sizeof(unsigned));

  int*      edge_cnt   = (int*)((char*)d_ws + o_ec);
  uint32_t* edge_words = (uint32_t*)((char*)d_ws + o_ew);
  unsigned long long* uvp = (unsigned long long*)((char*)d_ws + o_uv);
  unsigned* cnt        = (unsigned*)((char*)d_ws + o_ct);

  k_zero<<<1, 64, 0, stream>>>(cnt);
  k_fused<<<1 + TS + SCANB, SIMT, 0, stream>>>(H, edge_cnt, edge_words, uvp, cnt,
                                               x, beta, gamma_, out, keys);
}

// Round 8
// 1533.242 us; speedup vs baseline: 1.2256x; 1.1040x over previous
//
#include <hip/hip_runtime.h>
#include <stdint.h>

// JAX jax_threefry_partitionable=True semantics (verified exact, rounds 1-9).
// Round-18: PARALLEL SIM (4 blocks). Unified account of R10-R17: RPB=20 scan is
// ~150us (R13 occupancy trace); sim-alone is ~450-600us (15-20us/step) whether
// it reads via L2 (R16) or MALL (R17) => the sim is a one-CU ISSUE-WIDTH wall:
// ~940 scattered store instrs (240KB out/step) + node VALU + 20K LDS ops on 4
// SIMDs. Fix: slice nodes across 4 sim blocks (2500 each; p/beta/gamma/uniforms
// in regs, counts in private LDS slice), each holding a full 10KB st8 replica.
// Per step: gather all edges from replica (LDS, cheap), scatter only own slice,
// 1/4 the node+store issue, then AST-publish own 625-dword st8 quarter + tiny
// drain + fetch_add(scnt[t]); all poll scnt[t]==4 and refetch 2500 dwords.
// Edge/uv prefetch for t+1 rides the proven cntg gate. Scan/RNG roles unchanged.
constexpr int NN = 10000;          // nodes
constexpr int EE = 1000;           // hyperedges
constexpr int TT = 30;             // output rows
constexpr int TS = TT - 1;         // simulated steps
constexpr int ROW = NN * 3;        // floats per output row
constexpr int S_OFF = TT * ROW;    // state section offset in d_out
constexpr int CAP_E = 48;          // max nodes per edge (P(>=48) ~ 1e-30)
constexpr int WPR = CAP_E / 2;     // packed uint32 words per edge row
constexpr int PREW = 8;            // words prefetched unconditionally (covers ec<=16, ~97%)
constexpr int SIMT = 1024;         // block size (16 waves)
constexpr int NPT  = 10;           // full-range nodes per thread (init only)
constexpr int SIMW = 4;            // sim blocks (node slices)
constexpr int SLICE = NN / SIMW;   // 2500 nodes per sim block
constexpr int SNPT = (SLICE + SIMT - 1) / SIMT;  // 3 slice-nodes per thread
constexpr int STQ  = NN / 4;       // 2500 dwords of byte states (full)
constexpr int QW   = SLICE / 4;    // 625 dwords per slice quarter
constexpr int NROWS = TS * EE;     // 29000 total H rows
constexpr int F4R   = NN / 4;      // 2500 float4 per row
constexpr int RPB   = 20;          // H rows per scan block (divides EE => one t/block)
constexpr int PK    = 5;           // register pipeline depth in rows
constexpr int SCANB = NROWS / RPB; // 1450 scan blocks
constexpr unsigned GATE = EE + 1;  // 1000 scan rows + 1 RNG block per step
static_assert(EE % RPB == 0 && NROWS % RPB == 0 && RPB % PK == 0, "geometry");

// ---- Threefry-2x32, 20 rounds (exact JAX semantics), host+device ----
__host__ __device__ inline void tf2x32(uint32_t k0, uint32_t k1,
                                       uint32_t x0, uint32_t x1,
                                       uint32_t &o0, uint32_t &o1) {
  uint32_t ks2 = k0 ^ k1 ^ 0x1BD11BDAu;
  x0 += k0; x1 += k1;
#define TFR(r) do { x0 += x1; x1 = (x1 << (r)) | (x1 >> (32 - (r))); x1 ^= x0; } while (0)
  TFR(13); TFR(15); TFR(26); TFR(6);
  x0 += k1;  x1 += ks2 + 1u;
  TFR(17); TFR(29); TFR(16); TFR(24);
  x0 += ks2; x1 += k0 + 2u;
  TFR(13); TFR(15); TFR(26); TFR(6);
  x0 += k0;  x1 += k1 + 3u;
  TFR(17); TFR(29); TFR(16); TFR(24);
  x0 += k1;  x1 += ks2 + 4u;
  TFR(13); TFR(15); TFR(26); TFR(6);
  x0 += ks2; x1 += k0 + 5u;
#undef TFR
  o0 = x0; o1 = x1;
}

__device__ inline float bits_to_uniform(uint32_t bits) {
  float f = __uint_as_float((bits >> 9) | 0x3F800000u) - 1.0f;
  return f < 0.f ? 0.f : f;
}

struct StepKeys { uint32_t k1a[TS], k1b[TS], k2a[TS], k2b[TS]; };

// LDS-only barrier: orders LDS ops without draining global loads/stores (vmcnt).
__device__ inline void bar_lds() {
  asm volatile("s_waitcnt lgkmcnt(0)\n\ts_barrier" ::: "memory");
}

#define ALD(p)     __hip_atomic_load((p),  __ATOMIC_RELAXED, __HIP_MEMORY_SCOPE_AGENT)
#define AST(p, v)  __hip_atomic_store((p), (v), __ATOMIC_RELAXED, __HIP_MEMORY_SCOPE_AGENT)

// cnt/scnt live in d_ws (poisoned 0xAA every replay): zeroed before k_fused.
__global__ void k_zero(unsigned* __restrict__ cnt, unsigned* __restrict__ scnt) {
  if (threadIdx.x < TS) { cnt[threadIdx.x] = 0u; scnt[threadIdx.x] = 0u; }
}

__global__ __launch_bounds__(SIMT, 4)
void k_fused(const float* __restrict__ H,
             int* __restrict__ edge_cnt, uint32_t* __restrict__ edge_words,
             unsigned long long* __restrict__ uv, unsigned* __restrict__ cntg,
             unsigned* __restrict__ stbuf, unsigned* __restrict__ scnt,
             const float* __restrict__ x,
             const float* __restrict__ beta, const float* __restrict__ gamma_,
             float* __restrict__ out, StepKeys keys) {
  const int tid = threadIdx.x;
  const int bi  = blockIdx.x;

  if (bi >= SIMW && bi < SIMW + TS) {
    // ---- RNG role (dispatched early): step t uniforms -> uv, then +1 cnt[t] ----
    const int t = bi - SIMW;
#pragma unroll
    for (int k = 0; k < NPT; ++k) {
      int n = tid + k * SIMT;
      if (n < NN) {
        uint32_t a, b;
        tf2x32(keys.k1a[t], keys.k1b[t], 0u, (uint32_t)n, a, b);
        uint32_t b1 = __float_as_uint(bits_to_uniform(a ^ b));
        tf2x32(keys.k2a[t], keys.k2b[t], 0u, (uint32_t)n, a, b);
        uint32_t b2 = __float_as_uint(bits_to_uniform(a ^ b));
        unsigned long long raw = (unsigned long long)b1 | ((unsigned long long)b2 << 32);
        AST(&uv[(size_t)t * NN + n], raw);
      }
    }
    __syncthreads();  // s_waitcnt vmcnt(0): uv stores at MALL
    if (tid == 0)
      __hip_atomic_fetch_add(&cntg[t], 1u, __ATOMIC_RELAXED, __HIP_MEMORY_SCOPE_AGENT);
    return;
  }

  if (bi >= SIMW + TS) {
    // ---- scan role: RPB consecutive rows, rolling PK-deep register pipeline ----
    const int base = (bi - SIMW - TS) * RPB;
    const int t    = base / EE;          // single t per block (RPB | EE)
    const int e0   = base - t * EE;

    __shared__ int      scnt_arr[RPB];
    __shared__ uint16_t lists[RPB][CAP_E];
    if (tid < RPB) scnt_arr[tid] = 0;

    const float4* h0 = reinterpret_cast<const float4*>(H) + (size_t)base * F4R;
    const bool has2 = tid < F4R - 2048;  // tid < 452

    float4 b0[PK], b1[PK], b2[PK];
#pragma unroll
    for (int p = 0; p < PK; ++p) {       // prologue: PK rows (15 loads) in flight
      const float4* hr = h0 + (size_t)p * F4R;
      b0[p] = hr[tid];
      b1[p] = hr[tid + 1024];
      b2[p] = has2 ? hr[tid + 2048] : make_float4(0.f, 0.f, 0.f, 0.f);
    }
    bar_lds();                           // scnt_arr zeroed visible

#define PROCS(vv, b4, rr) do { \
    if ((vv).x != 0.f) { int q = atomicAdd(&scnt_arr[rr], 1); if (q < CAP_E) lists[rr][q] = (uint16_t)((b4) + 0); } \
    if ((vv).y != 0.f) { int q = atomicAdd(&scnt_arr[rr], 1); if (q < CAP_E) lists[rr][q] = (uint16_t)((b4) + 1); } \
    if ((vv).z != 0.f) { int q = atomicAdd(&scnt_arr[rr], 1); if (q < CAP_E) lists[rr][q] = (uint16_t)((b4) + 2); } \
    if ((vv).w != 0.f) { int q = atomicAdd(&scnt_arr[rr], 1); if (q < CAP_E) lists[rr][q] = (uint16_t)((b4) + 3); } \
  } while (0)

    for (int o = 0; o < RPB / PK; ++o) {
#pragma unroll
      for (int p = 0; p < PK; ++p) {     // static buffer index p: stays in VGPRs
        const int r = o * PK + p;
        float4 va = b0[p], vb = b1[p], vc = b2[p];
        if (o + 1 < RPB / PK) {          // refill row r+PK into slot p (uniform branch)
          const float4* hr = h0 + (size_t)(r + PK) * F4R;
          b0[p] = hr[tid];
          b1[p] = hr[tid + 1024];
          if (has2) b2[p] = hr[tid + 2048];
        }
        PROCS(va, 4 * tid, r);
        PROCS(vb, 4 * (tid + 1024), r);
        if (has2) PROCS(vc, 4 * (tid + 2048), r);
        bar_lds();                       // row r list complete (loads stay in flight)
        // publish row r via AST (MALL write-through); drained once at block end
        int c = scnt_arr[r]; c = c < CAP_E ? c : CAP_E;
        const int row = base + r, e = e0 + r;
        if (tid == 0) AST(&edge_cnt[row], c);
        int words = (c + 1) >> 1;
        int wmax = words > PREW ? words : PREW;   // sentinel-pad for sim prefetch
        if (tid < wmax) {
          uint32_t lo = (2 * tid     < c) ? (uint32_t)lists[r][2 * tid]     : 0xFFFFu;
          uint32_t hi = (2 * tid + 1 < c) ? (uint32_t)lists[r][2 * tid + 1] : 0xFFFFu;
          AST(&edge_words[((size_t)t * WPR + tid) * EE + e], lo | (hi << 16));
        }
      }
    }
#undef PROCS
    __syncthreads();  // s_waitcnt vmcnt(0): all edge stores at MALL
    if (tid == 0)
      __hip_atomic_fetch_add(&cntg[t], (unsigned)RPB,
                             __ATOMIC_RELAXED, __HIP_MEMORY_SCOPE_AGENT);
    return;
  }

  // ---------------- sim role: blocks 0..3, node slice each ----------------
  const int bs   = bi;                 // slice id
  const int base = bs * SLICE;
  __shared__ unsigned st8w[STQ];       // 10 KB: FULL state replica (bytes)
  __shared__ int      nv[SLICE];       // 10 KB: own-slice two-hop counts
  unsigned char* st8 = (unsigned char*)st8w;

  // init: full st8 replica from x; own slice p/beta/gamma in regs; row-0 out.
#pragma unroll
  for (int k = 0; k < NPT; ++k) {
    int n = tid + k * SIMT;
    if (n < NN) {
      float x0 = x[n * 3 + 0], x1 = x[n * 3 + 1];
      st8[n] = (unsigned char)((x1 == 1.f) ? 1 : ((x0 == 1.f) ? 0 : 2));
    }
  }
  float p0a[SNPT], p1a[SNPT], p2a[SNPT], bet[SNPT], gam[SNPT], u1r[SNPT], u2r[SNPT];
#pragma unroll
  for (int k = 0; k < SNPT; ++k) {
    int nl = tid + k * SIMT;
    if (nl < SLICE) {
      int n = base + nl;
      float x0 = x[n * 3 + 0], x1 = x[n * 3 + 1], x2 = x[n * 3 + 2];
      p0a[k] = x0; p1a[k] = x1; p2a[k] = x2;
      bet[k] = beta[n]; gam[k] = gamma_[n];
      out[n * 3 + 0] = x0; out[n * 3 + 1] = x1; out[n * 3 + 2] = x2;
      out[S_OFF + n * 3 + 0] = x0; out[S_OFF + n * 3 + 1] = x1; out[S_OFF + n * 3 + 2] = x2;
    }
  }
  for (int i = tid; i < SLICE; i += SIMT) nv[i] = 0;

  // gate t=0, then prefetch edge data (all edges) + own-slice uniforms
  if (tid == 0) {
    while (ALD(&cntg[0]) < GATE) __builtin_amdgcn_s_sleep(1);
  }
  bar_lds();   // gate seen; st8/nv init also ordered
  int ec = 0; uint32_t w[PREW];
  if (tid < EE) {
    ec = ALD(&edge_cnt[tid]); if (ec > CAP_E) ec = CAP_E;
#pragma unroll
    for (int j = 0; j < PREW; ++j) w[j] = ALD(&edge_words[(size_t)j * EE + tid]);
  }
#pragma unroll
  for (int k = 0; k < SNPT; ++k) {
    int nl = tid + k * SIMT;
    if (nl < SLICE) {
      unsigned long long raw = ALD(&uv[base + nl]);
      u1r[k] = __uint_as_float((uint32_t)raw);
      u2r[k] = __uint_as_float((uint32_t)(raw >> 32));
    }
  }

  for (int t = 0; t < TS; ++t) {
    // ---- edge phase: gather s from full replica; scatter only own slice ----
    if (tid < EE) {
      const uint32_t* wb = edge_words + (size_t)t * WPR * EE + tid;
      int words = (ec + 1) >> 1;
      int s = 0;
#pragma unroll
      for (int j = 0; j < PREW; ++j) {
        uint32_t lo = w[j] & 0xFFFFu, hi = w[j] >> 16;
        if (lo != 0xFFFFu) s += (st8[lo] == 1) ? 1 : 0;
        if (hi != 0xFFFFu) s += (st8[hi] == 1) ? 1 : 0;
      }
      for (int j = PREW; j < words; ++j) {   // rare tail (ec > 16)
        uint32_t ww = ALD(&wb[(size_t)j * EE]);
        uint32_t lo = ww & 0xFFFFu, hi = ww >> 16;
        if (lo != 0xFFFFu) s += (st8[lo] == 1) ? 1 : 0;
        if (hi != 0xFFFFu) s += (st8[hi] == 1) ? 1 : 0;
      }
      if (s > 0) {
#pragma unroll
        for (int j = 0; j < PREW; ++j) {
          unsigned r0 = (w[j] & 0xFFFFu) - (unsigned)base;       // sentinel lands OOB
          unsigned r1 = (w[j] >> 16) - (unsigned)base;
          if (r0 < (unsigned)SLICE) atomicAdd(&nv[r0], s);
          if (r1 < (unsigned)SLICE) atomicAdd(&nv[r1], s);
        }
        for (int j = PREW; j < words; ++j) {
          uint32_t ww = ALD(&wb[(size_t)j * EE]);
          unsigned r0 = (ww & 0xFFFFu) - (unsigned)base;
          unsigned r1 = (ww >> 16) - (unsigned)base;
          if (r0 < (unsigned)SLICE) atomicAdd(&nv[r0], s);
          if (r1 < (unsigned)SLICE) atomicAdd(&nv[r1], s);
        }
      }
    }
    bar_lds();  // nv counts complete

    // ---- node phase: own slice only (1/4 the VALU + store issue) ----
#pragma unroll
    for (int k = 0; k < SNPT; ++k) {
      int nl = tid + k * SIMT;
      if (nl < SLICE) {
        int n  = base + nl;
        int v  = nv[nl];
        int st = (int)st8[n];
        float s1 = (st == 1) ? 1.f : 0.f;
        float new_cases = __fmul_rn(bet[k], (float)v);
        float new_rec   = __fmul_rn(gam[k], s1);
        float q0 = fminf(1.f, fmaxf(0.f, __fsub_rn(p0a[k], new_cases)));
        float q1 = fminf(1.f, fmaxf(0.f, __fsub_rn(__fadd_rn(p1a[k], new_cases), new_rec)));
        float q2 = fminf(1.f, fmaxf(0.f, __fadd_rn(p2a[k], new_rec)));
        p0a[k] = q0; p1a[k] = q1; p2a[k] = q2;

        bool was_S  = (st == 0);
        bool was_I  = (st == 1);
        bool s_to_I = was_S && (u1r[k] < q1);
        bool i_event = was_I && (u1r[k] < q2);
        bool u2lt   = (u2r[k] < 0.5f);
        bool i_to_S = i_event && !u2lt;
        bool new_S = (was_S && !s_to_I) || i_to_S;
        bool new_I = s_to_I || (was_I && !i_event);
        st8[n] = (unsigned char)(new_I ? 1 : (new_S ? 0 : 2));
        nv[nl] = 0;                      // reset for next step
      }
    }
    bar_lds();  // st8 slice byte-writes visible for dword publish

    // ---- publish own st8 quarter (tiny drain), then fire-and-forget outputs ----
    if (tid < QW) AST(&stbuf[(size_t)t * STQ + bs * QW + tid], st8w[bs * QW + tid]);
    __syncthreads();  // s_waitcnt vmcnt(0): 625 dwords (prev-step out stores long done)
    if (tid == 0)
      __hip_atomic_fetch_add(&scnt[t], 1u, __ATOMIC_RELAXED, __HIP_MEMORY_SCOPE_AGENT);

    float* po = out + (size_t)(t + 1) * ROW;
    float* so = out + S_OFF + (size_t)(t + 1) * ROW;
#pragma unroll
    for (int k = 0; k < SNPT; ++k) {
      int nl = tid + k * SIMT;
      if (nl < SLICE) {
        int n = base + nl;
        po[n * 3 + 0] = p0a[k]; po[n * 3 + 1] = p1a[k]; po[n * 3 + 2] = p2a[k];
        int stn = (int)st8[n];
        so[n * 3 + 0] = (stn == 0) ? 1.f : 0.f;
        so[n * 3 + 1] = (stn == 1) ? 1.f : 0.f;
        so[n * 3 + 2] = (stn == 2) ? 1.f : 0.f;
      }
    }

    const bool more = (t + 1 < TS);
    if (more) {
      // gate + prefetch t+1 edge data and own-slice uniforms (latency overlapped)
      if (tid == 0) {
        while (ALD(&cntg[t + 1]) < GATE) __builtin_amdgcn_s_sleep(1);
      }
      bar_lds();
      int ecn = 0; uint32_t wn[PREW];
      if (tid < EE) {
        ecn = ALD(&edge_cnt[(t + 1) * EE + tid]); if (ecn > CAP_E) ecn = CAP_E;
#pragma unroll
        for (int j = 0; j < PREW; ++j)
          wn[j] = ALD(&edge_words[((size_t)(t + 1) * WPR + j) * EE + tid]);
      }
#pragma unroll
      for (int k = 0; k < SNPT; ++k) {
        int nl = tid + k * SIMT;
        if (nl < SLICE) {
          unsigned long long raw = ALD(&uv[(size_t)(t + 1) * NN + base + nl]);
          u1r[k] = __uint_as_float((uint32_t)raw);
          u2r[k] = __uint_as_float((uint32_t)(raw >> 32));
        }
      }
      // step gate: all 4 slices published; refetch full replica (values for own
      // slice are identical to what we already hold -- rewrite is harmless)
      if (tid == 0) {
        while (ALD(&scnt[t]) < (unsigned)SIMW) __builtin_amdgcn_s_sleep(1);
      }
      bar_lds();
      for (int i = tid; i < STQ; i += SIMT)
        st8w[i] = ALD(&stbuf[(size_t)t * STQ + i]);
      bar_lds();  // replica rebuilt
      ec = ecn;
#pragma unroll
      for (int j = 0; j < PREW; ++j) w[j] = wn[j];
    }
  }
}

extern "C" void kernel_launch(void* const* d_in, const int* in_sizes, int n_in,
                              void* d_out, int out_size, void* d_ws, size_t ws_size,
                              hipStream_t stream) {
  const float* x      = (const float*)d_in[0];
  const float* H      = (const float*)d_in[1];
  const float* beta   = (const float*)d_in[2];
  const float* gamma_ = (const float*)d_in[3];
  float* out = (float*)d_out;

  // key chain: key0 = jax.random.key(42) = (0,42); split(key,3) partitionable:
  // subkey i = threefry(key, (0,i)); carry = subkey 0.
  StepKeys keys;
  uint32_t key0 = 0u, key1 = 42u;
  for (int t = 0; t < TS; ++t) {
    uint32_t a0, b0, a1, b1, a2, b2;
    tf2x32(key0, key1, 0u, 0u, a0, b0);
    tf2x32(key0, key1, 0u, 1u, a1, b1);
    tf2x32(key0, key1, 0u, 2u, a2, b2);
    keys.k1a[t] = a1; keys.k1b[t] = b1; keys.k2a[t] = a2; keys.k2b[t] = b2;
    key0 = a0; key1 = b0;
  }

  // workspace layout (~5.6 MB)
  size_t off = 0;
  auto take = [&](size_t bytes) { size_t o = off; off += (bytes + 255) & ~(size_t)255; return o; };
  size_t o_ec = take((size_t)NROWS * sizeof(int));
  size_t o_ew = take((size_t)TS * WPR * EE * sizeof(uint32_t));
  size_t o_uv = take((size_t)TS * NN * sizeof(unsigned long long));
  size_t o_sb = take((size_t)TS * STQ * sizeof(unsigned));
  size_t o_ct = take((size_t)TS * sizeof(unsigned));
  size_t o_sc = take((size_t)TS * sizeof(unsigned));

  int*      edge_cnt   = (int*)((char*)d_ws + o_ec);
  uint32_t* edge_words = (uint32_t*)((char*)d_ws + o_ew);
  unsigned long long* uvp = (unsigned long long*)((char*)d_ws + o_uv);
  unsigned* stbuf      = (unsigned*)((char*)d_ws + o_sb);
  unsigned* cnt        = (unsigned*)((char*)d_ws + o_ct);
  unsigned* scn        = (unsigned*)((char*)d_ws + o_sc);

  k_zero<<<1, 64, 0, stream>>>(cnt, scn);
  k_fused<<<SIMW + TS + SCANB, SIMT, 0, stream>>>(H, edge_cnt, edge_words, uvp, cnt,
                                                  stbuf, scn, x, beta, gamma_, out, keys);
}